// Round 5
// baseline (323.010 us; speedup 1.0000x reference)
//
#include <hip/hip_runtime.h>

// FPN_AAR: FPN lateral/top-down + AdaptiveAngleConv (5 rotated 3x3) + SK fusion.
// Rotations are permutations of one kernel -> compute 9 tap planes
// S[s] = W[:,:,s] @ lat (one GEMM), then each rotation is a 9-term shifted
// gather of the planes (5x FLOP reduction vs direct conv).
// R5: gather L0/L1 via async global_load_lds staging (latency fix), XCD-swizzled
//     S-GEMM, c-split fc_att.

typedef unsigned short u16;
typedef unsigned int   u32;
typedef __bf16 bf16x8 __attribute__((ext_vector_type(8)));
typedef float  f32x4  __attribute__((ext_vector_type(4)));
typedef u16    u16x8  __attribute__((ext_vector_type(8)));
typedef u16    u16x4  __attribute__((ext_vector_type(4)));

__device__ __forceinline__ u16 f2b(float f) {  // f32 -> bf16 RNE
  u32 u = __builtin_bit_cast(u32, f);
  return (u16)((u + 0x7fffu + ((u >> 16) & 1u)) >> 16);
}
__device__ __forceinline__ float b2f(u16 h) {
  u32 u = ((u32)h) << 16;
  return __builtin_bit_cast(float, u);
}

constexpr int ROT[5][9] = {
  {0,1,2,3,4,5,6,7,8},
  {3,0,1,6,4,2,7,8,5},
  {6,3,0,7,4,1,8,5,2},
  {7,6,3,8,4,0,5,2,1},
  {8,7,6,5,4,3,2,1,0}};

__device__ __forceinline__ void glds16(const u16* g, u16* l) {
  __builtin_amdgcn_global_load_lds((const __attribute__((address_space(1))) void*)g,
                                   (__attribute__((address_space(3))) void*)l, 16, 0, 0);
}

// ---------------- param structs ----------------
struct PrepP {
  const float* x[4]; u16* xT[4];
  const float* lw[4]; u16* lwb[4];
  const float* aac_w; u16* W9[4];
};
struct LatP { const u16* A[4]; const u16* B[4]; float* O[4]; };
struct FinP { const float* In[4]; const float* bias; u16* latT_all; };
struct SgP  { const u16* A[4]; const u16* B[4]; u16* C[4]; int bid_base; };
struct GatP { const u16* S[4]; u16* feas[4]; float* fea_s; const u16* zb;
              const float* aac_b; const float* bn_g; const float* bn_b;
              const float* bn_m; const float* bn_v; int bid_base; };
struct CmbP { const u16* feas[4]; const float* att; float* out; int bid_base; };

// ---------------- merged prep: transpose + lw cvt + W9 permute ----------------
__global__ __launch_bounds__(256) void k_prep(PrepP P) {
  const int bid = blockIdx.x;
  const int tid = threadIdx.x;
  if (bid < 7680) {              // transpose f32 [C][P] -> bf16 [P][C]
    __shared__ u16 t[32][33];
    int lvl, local;
    if (bid < 4096)      { lvl = 0; local = bid; }
    else if (bid < 6144) { lvl = 1; local = bid - 4096; }
    else if (bid < 7168) { lvl = 2; local = bid - 6144; }
    else                 { lvl = 3; local = bid - 7168; }
    const float* src = P.x[lvl];
    u16* dst = P.xT[lvl];
    const int Pp = 16384 >> (2 * lvl);
    const int C = 256 << lvl;
    const int pbs = 9 - 2 * lvl;          // log2(P/32)
    int bx = local & ((1 << pbs) - 1), by = local >> pbs;
    int p0 = bx * 32, c0 = by * 32;
    int tx = tid & 31, ty = tid >> 5;
#pragma unroll
    for (int j = 0; j < 4; ++j)
      t[ty + 8 * j][tx] = f2b(src[(long)(c0 + ty + 8 * j) * Pp + p0 + tx]);
    __syncthreads();
#pragma unroll
    for (int j = 0; j < 4; ++j)
      dst[(long)(p0 + ty + 8 * j) * C + c0 + tx] = t[tx][ty + 8 * j];
  } else if (bid < 11520) {      // lw f32 -> bf16
    int i = (bid - 7680) * 256 + tid;
    const float* src; u16* dst; int off;
    if (i < 65536)       { src = P.lw[0]; dst = P.lwb[0]; off = i; }
    else if (i < 196608) { src = P.lw[1]; dst = P.lwb[1]; off = i - 65536; }
    else if (i < 458752) { src = P.lw[2]; dst = P.lwb[2]; off = i - 196608; }
    else                 { src = P.lw[3]; dst = P.lwb[3]; off = i - 458752; }
    dst[off] = f2b(src[off]);
  } else {                       // aac_w [4][256][256][9] -> W9 [(s*256+oc)][ic]
    int gid = (bid - 11520) * 256 + tid;
    int lvl = gid >> 16, idx = gid & 65535;
    u16* out = P.W9[lvl];
    const float* src = P.aac_w + (long)lvl * 589824 + (long)idx * 9;
    int oc = idx >> 8, ic = idx & 255;
    float v[9];
#pragma unroll
    for (int s = 0; s < 9; ++s) v[s] = src[s];
#pragma unroll
    for (int s = 0; s < 9; ++s) out[(long)((s << 8) + oc) * 256 + ic] = f2b(v[s]);
  }
}

// ---------------- lateral GEMM, split-K (chunk = 256) -------------------------
__global__ __launch_bounds__(256) void k_lat(LatP P) {
  constexpr int base[5] = {0, 256, 384, 448, 480};
  constexpr int NTS[4] = {7, 5, 3, 1};   // log2(N/128)
  int bid = blockIdx.x;
  int lvl = 0;
  while (bid >= base[lvl + 1]) ++lvl;
  int local = bid - base[lvl];
  const int nts = NTS[lvl];
  const int kc = local >> (nts + 1);
  const int r = local & ((2 << nts) - 1);
  const int by = r >> nts, bx = r & ((1 << nts) - 1);
  const int N = 16384 >> (2 * lvl);
  const long KF = 256 << lvl;
  const long kq = (long)kc * 256;
  const u16* A = P.A[lvl];
  const u16* B = P.B[lvl];
  float* O = P.O[lvl] + (long)kc * N * 256;

  __shared__ alignas(16) u16 As[128 * 32];
  __shared__ alignas(16) u16 Bs[128 * 32];
  const int tid = threadIdx.x;
  const int wid = tid >> 6, lane = tid & 63;
  const int wr = wid >> 1, wc = wid & 1;
  const int m0 = by * 128, n0 = bx * 128;
  const int lr = lane & 15, lk = lane >> 4;
  f32x4 acc[4][4] = {};
  const int t0 = wid * 2;
  const int srow = lane >> 2, scol = (lane & 3) * 8;
  const u16* gA0 = A + (long)(m0 + t0 * 16 + srow) * KF + kq + scol;
  const u16* gA1 = A + (long)(m0 + t0 * 16 + 16 + srow) * KF + kq + scol;
  const u16* gB0 = B + (long)(n0 + t0 * 16 + srow) * KF + kq + scol;
  const u16* gB1 = B + (long)(n0 + t0 * 16 + 16 + srow) * KF + kq + scol;
  u16* lA0 = As + t0 * 512;
  u16* lA1 = As + t0 * 512 + 512;
  u16* lB0 = Bs + t0 * 512;
  u16* lB1 = Bs + t0 * 512 + 512;
  for (int kt = 0; kt < 256; kt += 32) {
    glds16(gA0 + kt, lA0);
    glds16(gA1 + kt, lA1);
    glds16(gB0 + kt, lB0);
    glds16(gB1 + kt, lB1);
    __syncthreads();
    bf16x8 af[4], bfr[4];
#pragma unroll
    for (int m = 0; m < 4; ++m)
      af[m] = *(const bf16x8*)(As + (wr * 64 + m * 16 + lr) * 32 + lk * 8);
#pragma unroll
    for (int n = 0; n < 4; ++n)
      bfr[n] = *(const bf16x8*)(Bs + (wc * 64 + n * 16 + lr) * 32 + lk * 8);
#pragma unroll
    for (int m = 0; m < 4; ++m)
#pragma unroll
      for (int n = 0; n < 4; ++n)
        acc[m][n] = __builtin_amdgcn_mfma_f32_16x16x32_bf16(af[m], bfr[n], acc[m][n], 0, 0, 0);
    __syncthreads();
  }
#pragma unroll
  for (int m = 0; m < 4; ++m) {
    int row = m0 + wr * 64 + m * 16 + lk * 4;   // oc
#pragma unroll
    for (int n = 0; n < 4; ++n) {
      int col = n0 + wc * 64 + n * 16 + lr;     // pixel
      *(f32x4*)(O + (long)col * 256 + row) = acc[m][n];
    }
  }
}

// ---------------- finalize: sum chunks + bias -> latT bf16 --------------------
__global__ __launch_bounds__(256) void k_fin(FinP P) {
  constexpr long eb[5] = {0, 4194304, 5242880, 5505024, 5570560};
  long idx = ((long)blockIdx.x * 256 + threadIdx.x) * 8;
  int lvl = 0;
  while (idx >= eb[lvl + 1]) ++lvl;
  long local = idx - eb[lvl];
  const int chunks = 1 << lvl;
  const long cstride = (long)(16384 >> (2 * lvl)) * 256;
  const float* in = P.In[lvl] + local;
  f32x4 s0 = {0.f, 0.f, 0.f, 0.f}, s1 = {0.f, 0.f, 0.f, 0.f};
  for (int k = 0; k < chunks; ++k) {
    s0 += *(const f32x4*)(in + k * cstride);
    s1 += *(const f32x4*)(in + k * cstride + 4);
  }
  int oc = (int)(local & 255);
  const float* bias = P.bias + lvl * 256 + oc;
  f32x4 b0 = *(const f32x4*)bias;
  f32x4 b1 = *(const f32x4*)(bias + 4);
  u16x8 o;
#pragma unroll
  for (int i = 0; i < 4; ++i) { o[i] = f2b(s0[i] + b0[i]); o[4 + i] = f2b(s1[i] + b1[i]); }
  *(u16x8*)(P.latT_all + idx) = o;
}

// ---------------- upsample-add ----------------
__global__ void k_ups_add(u16* __restrict__ dst, const u16* __restrict__ src, int W, int HW) {
  int idx = blockIdx.x * 256 + threadIdx.x;
  int p = idx >> 5, c8 = (idx & 31) << 3;
  if (p >= HW) return;
  int y = p / W, x = p - y * W;
  int sp = (y >> 1) * (W >> 1) + (x >> 1);
  u16x8 d = *(const u16x8*)(dst + (long)p * 256 + c8);
  u16x8 s = *(const u16x8*)(src + (long)sp * 256 + c8);
  u16x8 o;
#pragma unroll
  for (int e = 0; e < 8; ++e) o[e] = f2b(b2f(d[e]) + b2f(s[e]));
  *(u16x8*)(dst + (long)p * 256 + c8) = o;
}

// ---------------- S-GEMM, XCD-swizzled so same-B-panel blocks share an L2 -----
__global__ __launch_bounds__(256) void k_sgemm(SgP P) {
  constexpr int base[5] = {0, 2304, 2880, 3024, 3060};
  constexpr int cntv[4] = {2304, 576, 144, 36};
  int bid = blockIdx.x + P.bid_base;
  int lvl = 0;
  while (bid >= base[lvl + 1]) ++lvl;
  int local = bid - base[lvl];
  if (lvl < 3) {                      // bijective XCD chunking (cnt % 8 == 0)
    int q = cntv[lvl] >> 3;
    local = (local & 7) * q + (local >> 3);
  }
  const int bx = local / 18, by = local - bx * 18;   // by fastest: B-panel reuse
  const int N = 16384 >> (2 * lvl);
  const u16* A = P.A[lvl];
  const u16* B = P.B[lvl];
  u16* C = P.C[lvl];

  __shared__ alignas(16) u16 As[128 * 32];
  __shared__ alignas(16) u16 Bs[128 * 32];
  const int tid = threadIdx.x;
  const int wid = tid >> 6, lane = tid & 63;
  const int wr = wid >> 1, wc = wid & 1;
  const int m0 = by * 128, n0 = bx * 128;
  const int lr = lane & 15, lk = lane >> 4;
  f32x4 acc[4][4] = {};
  const int t0 = wid * 2;
  const int srow = lane >> 2, scol = (lane & 3) * 8;
  const u16* gA0 = A + (long)(m0 + t0 * 16 + srow) * 256 + scol;
  const u16* gA1 = A + (long)(m0 + t0 * 16 + 16 + srow) * 256 + scol;
  const u16* gB0 = B + (long)(n0 + t0 * 16 + srow) * 256 + scol;
  const u16* gB1 = B + (long)(n0 + t0 * 16 + 16 + srow) * 256 + scol;
  u16* lA0 = As + t0 * 512;
  u16* lA1 = As + t0 * 512 + 512;
  u16* lB0 = Bs + t0 * 512;
  u16* lB1 = Bs + t0 * 512 + 512;
  for (int kt = 0; kt < 256; kt += 32) {
    glds16(gA0 + kt, lA0);
    glds16(gA1 + kt, lA1);
    glds16(gB0 + kt, lB0);
    glds16(gB1 + kt, lB1);
    __syncthreads();
    bf16x8 af[4], bfr[4];
#pragma unroll
    for (int m = 0; m < 4; ++m)
      af[m] = *(const bf16x8*)(As + (wr * 64 + m * 16 + lr) * 32 + lk * 8);
#pragma unroll
    for (int n = 0; n < 4; ++n)
      bfr[n] = *(const bf16x8*)(Bs + (wc * 64 + n * 16 + lr) * 32 + lk * 8);
#pragma unroll
    for (int m = 0; m < 4; ++m)
#pragma unroll
      for (int n = 0; n < 4; ++n)
        acc[m][n] = __builtin_amdgcn_mfma_f32_16x16x32_bf16(af[m], bfr[n], acc[m][n], 0, 0, 0);
    __syncthreads();
  }
#pragma unroll
  for (int m = 0; m < 4; ++m) {
    int row = m0 + wr * 64 + m * 16 + lk * 4;
#pragma unroll
    for (int n = 0; n < 4; ++n) {
      int col = n0 + wc * 64 + n * 16 + lr;
#pragma unroll
      for (int i = 0; i < 4; ++i)
        C[(long)(row + i) * N + col] = f2b(acc[m][n][i]);
    }
  }
}

// ---------------- gather: staged (L0/L1) and direct (L2/L3) -------------------
// Staged: block = (channel c, RB-row band). Async-stage 9 planes x (RB+2) rows
// of S (bf16, linear -> conflict-free) via global_load_lds, one barrier, then
// each thread computes 4 px from LDS b64 reads + shfl borders.
template <int LVL>
__device__ __forceinline__ void gather_staged(int local_bid, const GatP& P, u16* smB) {
  constexpr int W = (LVL == 0) ? 128 : 64, H = W, HW = W * W;
  constexpr int RB = (LVL == 0) ? 8 : 16;
  constexpr int RS = RB + 2;
  constexpr int CPR = W / 8;           // 16B chunks per row
  constexpr int XC = W / 4;            // 4-px thread columns per row
  constexpr int NS = 9 * RS * CPR;     // staged slots
  constexpr int KITER = (NS + 255) / 256;   // 6 for both levels
  constexpr int YB = H / RB;
  const int tid = threadIdx.x;
  const int c = local_bid / YB;
  const int y0 = (local_bid - c * YB) * RB;
  const u16* S = P.S[LVL];

  // ---- async stage ----
#pragma unroll
  for (int k = 0; k < KITER; ++k) {
    int slot = k * 256 + tid;
    int chunk = slot & (CPR - 1);
    int ldsrow = slot / CPR;
    const u16* src = P.zb;
    if (ldsrow < 9 * RS) {
      int s = ldsrow / RS;
      int r = ldsrow - s * RS;
      int y = y0 - 1 + r;
      if ((unsigned)y < (unsigned)H)
        src = S + (long)(s * 256 + c) * HW + (long)y * W + chunk * 8;
    }
    glds16(src, smB + (size_t)(slot & ~63) * 8);
  }

  float sc[5], sh[5];
#pragma unroll
  for (int m = 0; m < 5; ++m) {
    float g = P.bn_g[LVL * 1280 + m * 256 + c], bb = P.bn_b[LVL * 1280 + m * 256 + c];
    float mu = P.bn_m[LVL * 1280 + m * 256 + c], vv = P.bn_v[LVL * 1280 + m * 256 + c];
    float s = g * rsqrtf(vv + 1e-5f);
    sc[m] = s; sh[m] = bb - mu * s;
  }
  const float ab = P.aac_b[LVL * 256 + c];
  __syncthreads();                     // drains vmcnt (staging complete)

  const int xc = tid & (XC - 1);
  const int ro = tid / XC;
  float val[5][4];
#pragma unroll
  for (int m = 0; m < 5; ++m)
#pragma unroll
    for (int e = 0; e < 4; ++e) val[m][e] = ab;

#pragma unroll
  for (int dy = 0; dy < 3; ++dy) {
#pragma unroll
    for (int s = 0; s < 9; ++s) {
      bool used = false;
#pragma unroll
      for (int m = 0; m < 5; ++m)
#pragma unroll
        for (int dx = 0; dx < 3; ++dx)
          if (ROT[m][dy * 3 + dx] == s) used = true;
      if (!used) continue;             // compile-time folded
      int ldsrow = s * RS + ro + dy;
      u16x4 v = *(const u16x4*)(smB + (size_t)ldsrow * W + xc * 4);
      float f0 = b2f(v[0]), f1 = b2f(v[1]), f2 = b2f(v[2]), f3 = b2f(v[3]);
      float left = __shfl_up(f3, 1);
      float right = __shfl_down(f0, 1);
      if (xc == 0) left = 0.f;
      if (xc == XC - 1) right = 0.f;
      float wv[6] = {left, f0, f1, f2, f3, right};
#pragma unroll
      for (int m = 0; m < 5; ++m)
#pragma unroll
        for (int dx = 0; dx < 3; ++dx)
          if (ROT[m][dy * 3 + dx] == s) {
#pragma unroll
            for (int e = 0; e < 4; ++e) val[m][e] += wv[e + dx];
          }
    }
  }

  const int y = y0 + ro, x0 = xc * 4;
  float lsum = 0.f;
  u16* F = P.feas[LVL];
#pragma unroll
  for (int m = 0; m < 5; ++m) {
    u16x4 o;
#pragma unroll
    for (int e = 0; e < 4; ++e) {
      float r = fmaxf(val[m][e] * sc[m] + sh[m], 0.f);
      o[e] = f2b(r);
      lsum += r;
    }
    *(u16x4*)(F + (long)(m * 256 + c) * HW + (long)y * W + x0) = o;
  }
#pragma unroll
  for (int off = 32; off > 0; off >>= 1) lsum += __shfl_xor(lsum, off);
  if ((tid & 63) == 0) atomicAdd(P.fea_s + LVL * 256 + c, lsum);
}

// direct-global path for small levels (L2/L3)
template <int LVL>
__device__ __forceinline__ void gather_direct(int local_bid, const GatP& P) {
  constexpr int W = 128 >> LVL, H = W, HW = W * W;
  constexpr int XC = W / 8;
  constexpr int XS = 4 - LVL;
  constexpr int HS = 7 - LVL;
  const int tid = threadIdx.x;
  const int gid = local_bid * 256 + tid;
  const int xc = gid & (XC - 1);
  const int rem = gid >> XS;
  const int y = rem & (H - 1);
  const int c = rem >> HS;
  const u16* S = P.S[LVL];

  float sc[5], sh[5];
#pragma unroll
  for (int m = 0; m < 5; ++m) {
    float g = P.bn_g[LVL * 1280 + m * 256 + c], bb = P.bn_b[LVL * 1280 + m * 256 + c];
    float mu = P.bn_m[LVL * 1280 + m * 256 + c], vv = P.bn_v[LVL * 1280 + m * 256 + c];
    float s = g * rsqrtf(vv + 1e-5f);
    sc[m] = s; sh[m] = bb - mu * s;
  }
  const float ab = P.aac_b[LVL * 256 + c];
  float val[5][8];
#pragma unroll
  for (int m = 0; m < 5; ++m)
#pragma unroll
    for (int e = 0; e < 8; ++e) val[m][e] = ab;

#pragma unroll
  for (int dy = 0; dy < 3; ++dy) {
    const int row = y + dy - 1;
    const bool inr = (unsigned)row < (unsigned)H;
    const u16* Srow = S + (long)row * W + (xc << 3);
#pragma unroll
    for (int s = 0; s < 9; ++s) {
      bool used = false;
#pragma unroll
      for (int m = 0; m < 5; ++m)
#pragma unroll
        for (int dx = 0; dx < 3; ++dx)
          if (ROT[m][dy * 3 + dx] == s) used = true;
      if (!used) continue;
      u16x8 v = {0, 0, 0, 0, 0, 0, 0, 0};
      if (inr) v = *(const u16x8*)(Srow + (long)(s * 256 + c) * HW);
      float f[8];
#pragma unroll
      for (int j = 0; j < 8; ++j) f[j] = b2f(v[j]);
      float left = __shfl_up(f[7], 1);
      float right = __shfl_down(f[0], 1);
      if (xc == 0) left = 0.f;
      if (xc == XC - 1) right = 0.f;
      float wv[10];
      wv[0] = left;
#pragma unroll
      for (int j = 0; j < 8; ++j) wv[j + 1] = f[j];
      wv[9] = right;
#pragma unroll
      for (int m = 0; m < 5; ++m)
#pragma unroll
        for (int dx = 0; dx < 3; ++dx)
          if (ROT[m][dy * 3 + dx] == s) {
#pragma unroll
            for (int e = 0; e < 8; ++e) val[m][e] += wv[e + dx];
          }
    }
  }

  float lsum = 0.f;
  u16* F = P.feas[LVL];
#pragma unroll
  for (int m = 0; m < 5; ++m) {
    u16x8 o;
#pragma unroll
    for (int e = 0; e < 8; ++e) {
      float r = fmaxf(val[m][e] * sc[m] + sh[m], 0.f);
      o[e] = f2b(r);
      lsum += r;
    }
    *(u16x8*)(F + (long)(m * 256 + c) * HW + (long)y * W + (xc << 3)) = o;
  }
  constexpr int RG = (LVL == 3) ? 32 : 64;
#pragma unroll
  for (int off = RG >> 1; off > 0; off >>= 1) lsum += __shfl_xor(lsum, off);
  if ((tid & (RG - 1)) == 0) atomicAdd(P.fea_s + LVL * 256 + c, lsum);
}

__global__ __launch_bounds__(256) void k_gather(GatP P) {
  __shared__ alignas(16) u16 smB[12288];   // 24.6 KB: 6 blocks/CU
  int bid = blockIdx.x + P.bid_base;
  if (bid < 4096) gather_staged<0>(bid, P, smB);
  else if (bid < 5120) gather_staged<1>(bid - 4096, P, smB);
  else if (bid < 5248) gather_direct<2>(bid - 5120, P);
  else gather_direct<3>(bid - 5248, P);
}

// ---------------- FC + softmax attention (c-split: 8 blocks / level) ----------
__global__ __launch_bounds__(256) void k_fc_att(int lvl0, const float* __restrict__ fea_s,
                                                const float* __restrict__ fc_w,
                                                const float* __restrict__ fc_b,
                                                const float* __restrict__ fcs_w,
                                                const float* __restrict__ fcs_b,
                                                float* __restrict__ att) {
  const int lvl = lvl0 + (blockIdx.x >> 3);
  const int cb = (blockIdx.x & 7) * 32;
  const float inv_hw = 1.f / (float)(16384 >> (2 * lvl));
  __shared__ float ss[256], zs[128], lg[160];
  const int tid = threadIdx.x;
  ss[tid] = fea_s[lvl * 256 + tid] * inv_hw;
  __syncthreads();
  if (tid < 128) {                     // z = fc_b + fc_w @ ss (redundant per block)
    const f32x4* w4 = (const f32x4*)(fc_w + (long)lvl * 32768 + (long)tid * 256);
    float z = fc_b[lvl * 128 + tid];
#pragma unroll 8
    for (int j = 0; j < 64; ++j) {
      f32x4 w = w4[j];
      z += ss[4 * j] * w[0] + ss[4 * j + 1] * w[1] + ss[4 * j + 2] * w[2] + ss[4 * j + 3] * w[3];
    }
    zs[tid] = z;
  }
  __syncthreads();
  if (tid < 160) {                     // logits for this block's 32 channels
    int m = tid >> 5, ci = tid & 31;
    long row = (long)lvl * 1280 + m * 256 + cb + ci;
    const f32x4* w4 = (const f32x4*)(fcs_w + row * 128);
    float l = fcs_b[row];
#pragma unroll 8
    for (int d4 = 0; d4 < 32; ++d4) {
      f32x4 w = w4[d4];
      l += zs[4 * d4] * w[0] + zs[4 * d4 + 1] * w[1] + zs[4 * d4 + 2] * w[2] + zs[4 * d4 + 3] * w[3];
    }
    lg[tid] = l;
  }
  __syncthreads();
  if (tid < 32) {
    float v[5], mx = -1e30f;
#pragma unroll
    for (int m = 0; m < 5; ++m) { v[m] = lg[m * 32 + tid]; mx = fmaxf(mx, v[m]); }
    float se = 0.f;
#pragma unroll
    for (int m = 0; m < 5; ++m) { v[m] = __expf(v[m] - mx); se += v[m]; }
    float inv = 1.f / se;
#pragma unroll
    for (int m = 0; m < 5; ++m) att[(long)lvl * 1280 + m * 256 + cb + tid] = v[m] * inv;
  }
}

// ---------------- weighted combine (merged levels) ----------------
__global__ __launch_bounds__(256) void k_combine(CmbP P) {
  constexpr int base[5] = {0, 2048, 2560, 2688, 2720};
  constexpr long ooff[4] = {0, 4194304, 5242880, 5505024};
  int bid = blockIdx.x + P.bid_base;
  int lvl = 0;
  while (bid >= base[lvl + 1]) ++lvl;
  int local = bid - base[lvl];
  const int HW = 16384 >> (2 * lvl);
  const int hw8s = 11 - 2 * lvl;
  int idx = local * 256 + threadIdx.x;
  int c = idx >> hw8s;
  int p = (idx & ((1 << hw8s) - 1)) << 3;
  const u16* feas = P.feas[lvl];
  const float* att = P.att + lvl * 1280;
  float* out = P.out + ooff[lvl];
  float a[5];
#pragma unroll
  for (int m = 0; m < 5; ++m) a[m] = att[m * 256 + c];
  float o[8] = {};
#pragma unroll
  for (int m = 0; m < 5; ++m) {
    u16x8 v = *(const u16x8*)(feas + (long)(m * 256 + c) * HW + p);
#pragma unroll
    for (int e = 0; e < 8; ++e) o[e] += a[m] * b2f(v[e]);
  }
  float* op = out + (long)c * HW + p;
  f32x4 v0 = {o[0], o[1], o[2], o[3]};
  f32x4 v1 = {o[4], o[5], o[6], o[7]};
  *(f32x4*)op = v0;
  *(f32x4*)(op + 4) = v1;
}

// ---------------- host ----------------
extern "C" void kernel_launch(void* const* d_in, const int* in_sizes, int n_in,
                              void* d_out, int out_size, void* d_ws, size_t ws_size,
                              hipStream_t stream) {
  (void)n_in; (void)out_size;
  static const int HWs[4] = {16384, 4096, 1024, 256};
  static const int Ws[4]  = {128, 64, 32, 16};
  static const int Cin[4] = {256, 512, 1024, 2048};
  static const long LToff[4] = {0, 4194304, 5242880, 5505024};
  static const long SBoff[4] = {0, 37748736, 47185920, 49545216};
  static const long Foff[4]  = {0, 20971520, 26214400, 27525120};
  static const long Loff[4]  = {0, 4194304, 6291456, 7340032};

  int xi[4], li[4];
  if (in_sizes[1] == 256 * 256) {
    for (int i = 0; i < 4; ++i) { xi[i] = 2 * i; li[i] = 2 * i + 1; }
  } else {
    for (int i = 0; i < 4; ++i) { xi[i] = i; li[i] = 4 + i; }
  }
  const float *x[4], *lw[4];
  for (int i = 0; i < 4; ++i) { x[i] = (const float*)d_in[xi[i]]; lw[i] = (const float*)d_in[li[i]]; }
  const float* lb    = (const float*)d_in[8];
  const float* aac_w = (const float*)d_in[9];
  const float* aac_b = (const float*)d_in[10];
  const float* bn_g  = (const float*)d_in[11];
  const float* bn_b  = (const float*)d_in[12];
  const float* bn_m  = (const float*)d_in[13];
  const float* bn_v  = (const float*)d_in[14];
  const float* fc_w  = (const float*)d_in[15];
  const float* fc_b  = (const float*)d_in[16];
  const float* fcs_w = (const float*)d_in[17];
  const float* fcs_b = (const float*)d_in[18];

  char* wp = (char*)d_ws;
  auto carve = [&](size_t bytes) { char* p = wp; wp += (bytes + 255) & ~(size_t)255; return p; };
  u16* xT[4];  for (int i = 0; i < 4; ++i) xT[i]  = (u16*)carve((size_t)HWs[i] * Cin[i] * 2);
  u16* lwb[4]; for (int i = 0; i < 4; ++i) lwb[i] = (u16*)carve((size_t)256 * Cin[i] * 2);
  u16* latT_all = (u16*)carve((size_t)5570560 * 2);
  u16* W9[4];  for (int i = 0; i < 4; ++i) W9[i]  = (u16*)carve((size_t)2304 * 256 * 2);
  float* fea_s = (float*)carve(4 * 256 * 4);    // 4096 B
  u16* zbuf    = (u16*)carve(1024);             // zero pad source for OOB staging
  float* att   = (float*)carve(4 * 5 * 256 * 4);
  size_t fixed = (size_t)(wp - (char*)d_ws);
  const size_t szSbAll   = (size_t)50135040 * 2;
  const size_t szFeasAll = (size_t)27852800 * 2;
  const size_t szSbSh    = (size_t)37748736 * 2;
  const size_t szFeasSh  = (size_t)20971520 * 2;
  bool tierA = fixed + szSbAll + szFeasAll + 1024 <= ws_size;

  u16* Sb;     // aliased as f32 split-K chunk buffers before Sb is written
  u16* feasB;
  if (tierA) { Sb = (u16*)carve(szSbAll); feasB = (u16*)carve(szFeasAll); }
  else       { Sb = (u16*)carve(szSbSh);  feasB = (u16*)carve(szFeasSh); }
  float* latF32 = (float*)Sb;

  hipMemsetAsync(fea_s, 0, 4096 + 1024, stream);   // fea_s + zbuf (adjacent)

  // --- prep ---
  PrepP pp;
  for (int i = 0; i < 4; ++i) {
    pp.x[i] = x[i]; pp.xT[i] = xT[i]; pp.lw[i] = lw[i]; pp.lwb[i] = lwb[i]; pp.W9[i] = W9[i];
  }
  pp.aac_w = aac_w;
  k_prep<<<12544, 256, 0, stream>>>(pp);

  // --- lateral GEMM (split-K) + finalize + top-down ---
  LatP lp;
  for (int i = 0; i < 4; ++i) { lp.A[i] = lwb[i]; lp.B[i] = xT[i]; lp.O[i] = latF32 + Loff[i]; }
  k_lat<<<480, 256, 0, stream>>>(lp);
  FinP fp;
  for (int i = 0; i < 4; ++i) fp.In[i] = latF32 + Loff[i];
  fp.bias = lb; fp.latT_all = latT_all;
  k_fin<<<2720, 256, 0, stream>>>(fp);
  for (int i = 2; i >= 0; --i)
    k_ups_add<<<HWs[i] / 8, 256, 0, stream>>>(latT_all + LToff[i], latT_all + LToff[i + 1],
                                              Ws[i], HWs[i]);

  static const int cnt_s[4] = {2304, 576, 144, 36};
  static const int base_s[4] = {0, 2304, 2880, 3024};
  static const int cnt_g[4] = {4096, 1024, 128, 32};
  static const int base_g[4] = {0, 4096, 5120, 5248};
  static const int cnt_c[4] = {2048, 512, 128, 32};
  static const int base_c[4] = {0, 2048, 2560, 2688};

  SgP sp;
  GatP gp;
  CmbP cp;
  for (int i = 0; i < 4; ++i) {
    sp.A[i] = W9[i];
    sp.B[i] = latT_all + LToff[i];
    sp.C[i] = tierA ? Sb + SBoff[i] : Sb;
    gp.S[i] = sp.C[i];
    gp.feas[i] = tierA ? feasB + Foff[i] : feasB;
    cp.feas[i] = gp.feas[i];
  }
  gp.fea_s = fea_s;
  gp.zb = zbuf;
  gp.aac_b = aac_b; gp.bn_g = bn_g; gp.bn_b = bn_b; gp.bn_m = bn_m; gp.bn_v = bn_v;
  cp.att = att; cp.out = (float*)d_out;

  if (tierA) {
    sp.bid_base = 0; gp.bid_base = 0; cp.bid_base = 0;
    k_sgemm<<<3060, 256, 0, stream>>>(sp);
    k_gather<<<5280, 256, 0, stream>>>(gp);
    k_fc_att<<<32, 256, 0, stream>>>(0, fea_s, fc_w, fc_b, fcs_w, fcs_b, att);
    k_combine<<<2720, 256, 0, stream>>>(cp);
  } else {
    for (int i = 0; i < 4; ++i) {
      sp.bid_base = base_s[i];
      k_sgemm<<<cnt_s[i], 256, 0, stream>>>(sp);
      gp.bid_base = base_g[i];
      k_gather<<<cnt_g[i], 256, 0, stream>>>(gp);
      k_fc_att<<<8, 256, 0, stream>>>(i, fea_s, fc_w, fc_b, fcs_w, fcs_b, att);
      cp.bid_base = base_c[i];
      k_combine<<<cnt_c[i], 256, 0, stream>>>(cp);
    }
  }
}

// Round 6
// 287.645 us; speedup vs baseline: 1.1229x; 1.1229x over previous
//
#include <hip/hip_runtime.h>

// FPN_AAR: FPN lateral/top-down + AdaptiveAngleConv (5 rotated 3x3) + SK fusion.
// Rotations are permutations of one kernel -> compute 9 tap planes
// S[s] = W[:,:,s] @ lat (one GEMM), then each rotation is a 9-term shifted
// gather of the planes (5x FLOP reduction vs direct conv).
// R6: streaming gather — block = (c, y-band); 9 sequential 4.5KB plane streams,
//     dy-halo re-reads served by L1, coalesced full-row loads, no LDS/barrier.
//     Lateral L0 writes bf16+bias directly (skips f32 finalize round-trip).

typedef unsigned short u16;
typedef unsigned int   u32;
typedef __bf16 bf16x8 __attribute__((ext_vector_type(8)));
typedef float  f32x4  __attribute__((ext_vector_type(4)));
typedef u16    u16x8  __attribute__((ext_vector_type(8)));
typedef u16    u16x4  __attribute__((ext_vector_type(4)));

__device__ __forceinline__ u16 f2b(float f) {  // f32 -> bf16 RNE
  u32 u = __builtin_bit_cast(u32, f);
  return (u16)((u + 0x7fffu + ((u >> 16) & 1u)) >> 16);
}
__device__ __forceinline__ float b2f(u16 h) {
  u32 u = ((u32)h) << 16;
  return __builtin_bit_cast(float, u);
}

constexpr int ROT[5][9] = {
  {0,1,2,3,4,5,6,7,8},
  {3,0,1,6,4,2,7,8,5},
  {6,3,0,7,4,1,8,5,2},
  {7,6,3,8,4,0,5,2,1},
  {8,7,6,5,4,3,2,1,0}};

__device__ __forceinline__ void glds16(const u16* g, u16* l) {
  __builtin_amdgcn_global_load_lds((const __attribute__((address_space(1))) void*)g,
                                   (__attribute__((address_space(3))) void*)l, 16, 0, 0);
}

// ---------------- param structs ----------------
struct PrepP {
  const float* x[4]; u16* xT[4];
  const float* lw[4]; u16* lwb[4];
  const float* aac_w; u16* W9[4];
};
struct LatP { const u16* A[4]; const u16* B[4]; float* O[4];
              const float* bias0; u16* latT0; };
struct FinP { const float* In[4]; const float* bias; u16* latT_all; };
struct SgP  { const u16* A[4]; const u16* B[4]; u16* C[4]; int bid_base; };
struct GatP { const u16* S[4]; u16* feas[4]; float* fea_s;
              const float* aac_b; const float* bn_g; const float* bn_b;
              const float* bn_m; const float* bn_v; int bid_base; };
struct CmbP { const u16* feas[4]; const float* att; float* out; int bid_base; };

// ---------------- merged prep: transpose + lw cvt + W9 permute ----------------
__global__ __launch_bounds__(256) void k_prep(PrepP P) {
  const int bid = blockIdx.x;
  const int tid = threadIdx.x;
  if (bid < 7680) {              // transpose f32 [C][P] -> bf16 [P][C]
    __shared__ u16 t[32][33];
    int lvl, local;
    if (bid < 4096)      { lvl = 0; local = bid; }
    else if (bid < 6144) { lvl = 1; local = bid - 4096; }
    else if (bid < 7168) { lvl = 2; local = bid - 6144; }
    else                 { lvl = 3; local = bid - 7168; }
    const float* src = P.x[lvl];
    u16* dst = P.xT[lvl];
    const int Pp = 16384 >> (2 * lvl);
    const int C = 256 << lvl;
    const int pbs = 9 - 2 * lvl;          // log2(P/32)
    int bx = local & ((1 << pbs) - 1), by = local >> pbs;
    int p0 = bx * 32, c0 = by * 32;
    int tx = tid & 31, ty = tid >> 5;
#pragma unroll
    for (int j = 0; j < 4; ++j)
      t[ty + 8 * j][tx] = f2b(src[(long)(c0 + ty + 8 * j) * Pp + p0 + tx]);
    __syncthreads();
#pragma unroll
    for (int j = 0; j < 4; ++j)
      dst[(long)(p0 + ty + 8 * j) * C + c0 + tx] = t[tx][ty + 8 * j];
  } else if (bid < 11520) {      // lw f32 -> bf16
    int i = (bid - 7680) * 256 + tid;
    const float* src; u16* dst; int off;
    if (i < 65536)       { src = P.lw[0]; dst = P.lwb[0]; off = i; }
    else if (i < 196608) { src = P.lw[1]; dst = P.lwb[1]; off = i - 65536; }
    else if (i < 458752) { src = P.lw[2]; dst = P.lwb[2]; off = i - 196608; }
    else                 { src = P.lw[3]; dst = P.lwb[3]; off = i - 458752; }
    dst[off] = f2b(src[off]);
  } else {                       // aac_w [4][256][256][9] -> W9 [(s*256+oc)][ic]
    int gid = (bid - 11520) * 256 + tid;
    int lvl = gid >> 16, idx = gid & 65535;
    u16* out = P.W9[lvl];
    const float* src = P.aac_w + (long)lvl * 589824 + (long)idx * 9;
    int oc = idx >> 8, ic = idx & 255;
    float v[9];
#pragma unroll
    for (int s = 0; s < 9; ++s) v[s] = src[s];
#pragma unroll
    for (int s = 0; s < 9; ++s) out[(long)((s << 8) + oc) * 256 + ic] = f2b(v[s]);
  }
}

// ---------------- lateral GEMM, split-K (chunk = 256) -------------------------
// lvl 0 has a single K-chunk: write bf16 transposed + bias directly.
__global__ __launch_bounds__(256) void k_lat(LatP P) {
  constexpr int base[5] = {0, 256, 384, 448, 480};
  constexpr int NTS[4] = {7, 5, 3, 1};   // log2(N/128)
  int bid = blockIdx.x;
  int lvl = 0;
  while (bid >= base[lvl + 1]) ++lvl;
  int local = bid - base[lvl];
  const int nts = NTS[lvl];
  const int kc = local >> (nts + 1);
  const int r = local & ((2 << nts) - 1);
  const int by = r >> nts, bx = r & ((1 << nts) - 1);
  const int N = 16384 >> (2 * lvl);
  const long KF = 256 << lvl;
  const long kq = (long)kc * 256;
  const u16* A = P.A[lvl];
  const u16* B = P.B[lvl];
  float* O = P.O[lvl] + (long)kc * N * 256;

  __shared__ alignas(16) u16 As[128 * 32];
  __shared__ alignas(16) u16 Bs[128 * 32];
  const int tid = threadIdx.x;
  const int wid = tid >> 6, lane = tid & 63;
  const int wr = wid >> 1, wc = wid & 1;
  const int m0 = by * 128, n0 = bx * 128;
  const int lr = lane & 15, lk = lane >> 4;
  f32x4 acc[4][4] = {};
  const int t0 = wid * 2;
  const int srow = lane >> 2, scol = (lane & 3) * 8;
  const u16* gA0 = A + (long)(m0 + t0 * 16 + srow) * KF + kq + scol;
  const u16* gA1 = A + (long)(m0 + t0 * 16 + 16 + srow) * KF + kq + scol;
  const u16* gB0 = B + (long)(n0 + t0 * 16 + srow) * KF + kq + scol;
  const u16* gB1 = B + (long)(n0 + t0 * 16 + 16 + srow) * KF + kq + scol;
  u16* lA0 = As + t0 * 512;
  u16* lA1 = As + t0 * 512 + 512;
  u16* lB0 = Bs + t0 * 512;
  u16* lB1 = Bs + t0 * 512 + 512;
  for (int kt = 0; kt < 256; kt += 32) {
    glds16(gA0 + kt, lA0);
    glds16(gA1 + kt, lA1);
    glds16(gB0 + kt, lB0);
    glds16(gB1 + kt, lB1);
    __syncthreads();
    bf16x8 af[4], bfr[4];
#pragma unroll
    for (int m = 0; m < 4; ++m)
      af[m] = *(const bf16x8*)(As + (wr * 64 + m * 16 + lr) * 32 + lk * 8);
#pragma unroll
    for (int n = 0; n < 4; ++n)
      bfr[n] = *(const bf16x8*)(Bs + (wc * 64 + n * 16 + lr) * 32 + lk * 8);
#pragma unroll
    for (int m = 0; m < 4; ++m)
#pragma unroll
      for (int n = 0; n < 4; ++n)
        acc[m][n] = __builtin_amdgcn_mfma_f32_16x16x32_bf16(af[m], bfr[n], acc[m][n], 0, 0, 0);
    __syncthreads();
  }
  if (lvl == 0) {                        // single chunk: direct bf16 + bias
#pragma unroll
    for (int m = 0; m < 4; ++m) {
      int row = m0 + wr * 64 + m * 16 + lk * 4;
      f32x4 bv = *(const f32x4*)(P.bias0 + row);
#pragma unroll
      for (int n = 0; n < 4; ++n) {
        int col = n0 + wc * 64 + n * 16 + lr;
        u16x4 o;
#pragma unroll
        for (int i = 0; i < 4; ++i) o[i] = f2b(acc[m][n][i] + bv[i]);
        *(u16x4*)(P.latT0 + (long)col * 256 + row) = o;
      }
    }
  } else {
#pragma unroll
    for (int m = 0; m < 4; ++m) {
      int row = m0 + wr * 64 + m * 16 + lk * 4;   // oc
#pragma unroll
      for (int n = 0; n < 4; ++n) {
        int col = n0 + wc * 64 + n * 16 + lr;     // pixel
        *(f32x4*)(O + (long)col * 256 + row) = acc[m][n];
      }
    }
  }
}

// ---------------- finalize levels 1-3: sum chunks + bias -> latT bf16 ---------
__global__ __launch_bounds__(256) void k_fin(FinP P) {
  constexpr long eb[5] = {0, 4194304, 5242880, 5505024, 5570560};
  long idx = 4194304 + ((long)blockIdx.x * 256 + threadIdx.x) * 8;
  int lvl = 1;
  while (idx >= eb[lvl + 1]) ++lvl;
  long local = idx - eb[lvl];
  const int chunks = 1 << lvl;
  const long cstride = (long)(16384 >> (2 * lvl)) * 256;
  const float* in = P.In[lvl] + local;
  f32x4 s0 = {0.f, 0.f, 0.f, 0.f}, s1 = {0.f, 0.f, 0.f, 0.f};
  for (int k = 0; k < chunks; ++k) {
    s0 += *(const f32x4*)(in + k * cstride);
    s1 += *(const f32x4*)(in + k * cstride + 4);
  }
  int oc = (int)(local & 255);
  const float* bias = P.bias + lvl * 256 + oc;
  f32x4 b0 = *(const f32x4*)bias;
  f32x4 b1 = *(const f32x4*)(bias + 4);
  u16x8 o;
#pragma unroll
  for (int i = 0; i < 4; ++i) { o[i] = f2b(s0[i] + b0[i]); o[4 + i] = f2b(s1[i] + b1[i]); }
  *(u16x8*)(P.latT_all + idx) = o;
}

// ---------------- upsample-add ----------------
__global__ void k_ups_add(u16* __restrict__ dst, const u16* __restrict__ src, int W, int HW) {
  int idx = blockIdx.x * 256 + threadIdx.x;
  int p = idx >> 5, c8 = (idx & 31) << 3;
  if (p >= HW) return;
  int y = p / W, x = p - y * W;
  int sp = (y >> 1) * (W >> 1) + (x >> 1);
  u16x8 d = *(const u16x8*)(dst + (long)p * 256 + c8);
  u16x8 s = *(const u16x8*)(src + (long)sp * 256 + c8);
  u16x8 o;
#pragma unroll
  for (int e = 0; e < 8; ++e) o[e] = f2b(b2f(d[e]) + b2f(s[e]));
  *(u16x8*)(dst + (long)p * 256 + c8) = o;
}

// ---------------- S-GEMM, XCD-swizzled so same-B-panel blocks share an L2 -----
__global__ __launch_bounds__(256) void k_sgemm(SgP P) {
  constexpr int base[5] = {0, 2304, 2880, 3024, 3060};
  constexpr int cntv[4] = {2304, 576, 144, 36};
  int bid = blockIdx.x + P.bid_base;
  int lvl = 0;
  while (bid >= base[lvl + 1]) ++lvl;
  int local = bid - base[lvl];
  if (lvl < 3) {                      // bijective XCD chunking (cnt % 8 == 0)
    int q = cntv[lvl] >> 3;
    local = (local & 7) * q + (local >> 3);
  }
  const int bx = local / 18, by = local - bx * 18;   // by fastest: B-panel reuse
  const int N = 16384 >> (2 * lvl);
  const u16* A = P.A[lvl];
  const u16* B = P.B[lvl];
  u16* C = P.C[lvl];

  __shared__ alignas(16) u16 As[128 * 32];
  __shared__ alignas(16) u16 Bs[128 * 32];
  const int tid = threadIdx.x;
  const int wid = tid >> 6, lane = tid & 63;
  const int wr = wid >> 1, wc = wid & 1;
  const int m0 = by * 128, n0 = bx * 128;
  const int lr = lane & 15, lk = lane >> 4;
  f32x4 acc[4][4] = {};
  const int t0 = wid * 2;
  const int srow = lane >> 2, scol = (lane & 3) * 8;
  const u16* gA0 = A + (long)(m0 + t0 * 16 + srow) * 256 + scol;
  const u16* gA1 = A + (long)(m0 + t0 * 16 + 16 + srow) * 256 + scol;
  const u16* gB0 = B + (long)(n0 + t0 * 16 + srow) * 256 + scol;
  const u16* gB1 = B + (long)(n0 + t0 * 16 + 16 + srow) * 256 + scol;
  u16* lA0 = As + t0 * 512;
  u16* lA1 = As + t0 * 512 + 512;
  u16* lB0 = Bs + t0 * 512;
  u16* lB1 = Bs + t0 * 512 + 512;
  for (int kt = 0; kt < 256; kt += 32) {
    glds16(gA0 + kt, lA0);
    glds16(gA1 + kt, lA1);
    glds16(gB0 + kt, lB0);
    glds16(gB1 + kt, lB1);
    __syncthreads();
    bf16x8 af[4], bfr[4];
#pragma unroll
    for (int m = 0; m < 4; ++m)
      af[m] = *(const bf16x8*)(As + (wr * 64 + m * 16 + lr) * 32 + lk * 8);
#pragma unroll
    for (int n = 0; n < 4; ++n)
      bfr[n] = *(const bf16x8*)(Bs + (wc * 64 + n * 16 + lr) * 32 + lk * 8);
#pragma unroll
    for (int m = 0; m < 4; ++m)
#pragma unroll
      for (int n = 0; n < 4; ++n)
        acc[m][n] = __builtin_amdgcn_mfma_f32_16x16x32_bf16(af[m], bfr[n], acc[m][n], 0, 0, 0);
    __syncthreads();
  }
#pragma unroll
  for (int m = 0; m < 4; ++m) {
    int row = m0 + wr * 64 + m * 16 + lk * 4;
#pragma unroll
    for (int n = 0; n < 4; ++n) {
      int col = n0 + wc * 64 + n * 16 + lr;
#pragma unroll
      for (int i = 0; i < 4; ++i)
        C[(long)(row + i) * N + col] = f2b(acc[m][n][i]);
    }
  }
}

// ---------------- streaming gather + BN + ReLU + channel-sum ------------------
// Block = (channel(s), y-band). Each thread owns 8 consecutive px of one row.
// Per plane s the block reads consecutive rows of plane (s,c): long sequential
// DRAM streams; the 3x dy-overlap is served by L1. Coalesced u16x8 loads
// (16 lanes x 16B = full 256B row at L0). x-halo via shfl within row-groups
// (group boundaries == image borders). No LDS, no barriers.
__device__ __forceinline__ constexpr bool rot_used(int s, int dy) {
  bool u = false;
  for (int m = 0; m < 5; ++m)
    for (int dx = 0; dx < 3; ++dx)
      if (ROT[m][dy * 3 + dx] == s) u = true;
  return u;
}

template <int LVL>
__device__ __forceinline__ void gather_stream(int local_bid, const GatP& P) {
  constexpr int W = 128 >> LVL, H = W, HW = W * W;
  constexpr int XL = 16 >> LVL;                    // lanes per row (8 px each)
  constexpr int LX = 4 - LVL;                      // log2 XL
  constexpr int YB = (LVL == 0 || LVL == 3) ? 16 : 32;
  constexpr int LY = (LVL == 0 || LVL == 3) ? 4 : 5;
  constexpr int NB = H / YB;                       // y-bands (8,2,1,1)
  constexpr int CPB = 256 / (XL * YB);             // channels/block (1,1,2,8)
  const int tid = threadIdx.x;
  const int xc = tid & (XL - 1);
  const int yloc = (tid >> LX) & (YB - 1);
  const int csub = tid >> (LX + LY);
  const int band = local_bid & (NB - 1);
  const int c = (local_bid / NB) * CPB + csub;
  const int y = band * YB + yloc;
  const u16* Sb = P.S[LVL] + (long)c * HW + (long)y * W + xc * 8;

  float sc[5], sh[5];
#pragma unroll
  for (int m = 0; m < 5; ++m) {
    float g = P.bn_g[LVL * 1280 + m * 256 + c], bb = P.bn_b[LVL * 1280 + m * 256 + c];
    float mu = P.bn_m[LVL * 1280 + m * 256 + c], vv = P.bn_v[LVL * 1280 + m * 256 + c];
    float s = g * rsqrtf(vv + 1e-5f);
    sc[m] = s; sh[m] = bb - mu * s;
  }
  const float ab = P.aac_b[LVL * 256 + c];
  float val[5][8];
#pragma unroll
  for (int m = 0; m < 5; ++m)
#pragma unroll
    for (int e = 0; e < 8; ++e) val[m][e] = ab;

  const bool hasm = (y > 0), hasp = (y < H - 1);
#pragma unroll
  for (int s = 0; s < 9; ++s) {
    const u16* bp = Sb + (long)s * 256 * HW;
    constexpr u16x8 Z = {0, 0, 0, 0, 0, 0, 0, 0};
    u16x8 vrow[3];
    if constexpr (rot_used(0, 0)) {}             // (keep constexpr fn referenced)
#pragma unroll
    for (int dy = 0; dy < 3; ++dy) {
      bool used = rot_used(s, dy);
      if (!used) continue;
      u16x8 v = Z;
      if (dy == 0) { if (hasm) v = *(const u16x8*)(bp - W); }
      else if (dy == 1) { v = *(const u16x8*)bp; }
      else { if (hasp) v = *(const u16x8*)(bp + W); }
      vrow[dy] = v;
    }
#pragma unroll
    for (int dy = 0; dy < 3; ++dy) {
      if (!rot_used(s, dy)) continue;
      float f[8];
#pragma unroll
      for (int j = 0; j < 8; ++j) f[j] = b2f(vrow[dy][j]);
      float left = __shfl_up(f[7], 1);
      float right = __shfl_down(f[0], 1);
      if (xc == 0) left = 0.f;
      if (xc == XL - 1) right = 0.f;
      float wv[10];
      wv[0] = left;
#pragma unroll
      for (int j = 0; j < 8; ++j) wv[j + 1] = f[j];
      wv[9] = right;
#pragma unroll
      for (int m = 0; m < 5; ++m)
#pragma unroll
        for (int dx = 0; dx < 3; ++dx)
          if (ROT[m][dy * 3 + dx] == s) {
#pragma unroll
            for (int e = 0; e < 8; ++e) val[m][e] += wv[e + dx];
          }
    }
  }

  float lsum = 0.f;
  u16* F = P.feas[LVL];
#pragma unroll
  for (int m = 0; m < 5; ++m) {
    u16x8 o;
#pragma unroll
    for (int e = 0; e < 8; ++e) {
      float r = fmaxf(val[m][e] * sc[m] + sh[m], 0.f);
      o[e] = f2b(r);
      lsum += r;
    }
    *(u16x8*)(F + (long)(m * 256 + c) * HW + (long)y * W + xc * 8) = o;
  }
  constexpr int RG = (LVL == 3) ? 32 : 64;         // lanes sharing one channel
#pragma unroll
  for (int off = RG >> 1; off > 0; off >>= 1) lsum += __shfl_xor(lsum, off);
  if ((tid & (RG - 1)) == 0) atomicAdd(P.fea_s + LVL * 256 + c, lsum);
}

__global__ __launch_bounds__(256) void k_gather(GatP P) {
  int bid = blockIdx.x + P.bid_base;
  if (bid < 2048) gather_stream<0>(bid, P);
  else if (bid < 2560) gather_stream<1>(bid - 2048, P);
  else if (bid < 2688) gather_stream<2>(bid - 2560, P);
  else gather_stream<3>(bid - 2688, P);
}

// ---------------- FC + softmax attention (c-split: 8 blocks / level) ----------
__global__ __launch_bounds__(256) void k_fc_att(int lvl0, const float* __restrict__ fea_s,
                                                const float* __restrict__ fc_w,
                                                const float* __restrict__ fc_b,
                                                const float* __restrict__ fcs_w,
                                                const float* __restrict__ fcs_b,
                                                float* __restrict__ att) {
  const int lvl = lvl0 + (blockIdx.x >> 3);
  const int cb = (blockIdx.x & 7) * 32;
  const float inv_hw = 1.f / (float)(16384 >> (2 * lvl));
  __shared__ float ss[256], zs[128], lg[160];
  const int tid = threadIdx.x;
  ss[tid] = fea_s[lvl * 256 + tid] * inv_hw;
  __syncthreads();
  if (tid < 128) {                     // z = fc_b + fc_w @ ss (redundant per block)
    const f32x4* w4 = (const f32x4*)(fc_w + (long)lvl * 32768 + (long)tid * 256);
    float z = fc_b[lvl * 128 + tid];
#pragma unroll 8
    for (int j = 0; j < 64; ++j) {
      f32x4 w = w4[j];
      z += ss[4 * j] * w[0] + ss[4 * j + 1] * w[1] + ss[4 * j + 2] * w[2] + ss[4 * j + 3] * w[3];
    }
    zs[tid] = z;
  }
  __syncthreads();
  if (tid < 160) {                     // logits for this block's 32 channels
    int m = tid >> 5, ci = tid & 31;
    long row = (long)lvl * 1280 + m * 256 + cb + ci;
    const f32x4* w4 = (const f32x4*)(fcs_w + row * 128);
    float l = fcs_b[row];
#pragma unroll 8
    for (int d4 = 0; d4 < 32; ++d4) {
      f32x4 w = w4[d4];
      l += zs[4 * d4] * w[0] + zs[4 * d4 + 1] * w[1] + zs[4 * d4 + 2] * w[2] + zs[4 * d4 + 3] * w[3];
    }
    lg[tid] = l;
  }
  __syncthreads();
  if (tid < 32) {
    float v[5], mx = -1e30f;
#pragma unroll
    for (int m = 0; m < 5; ++m) { v[m] = lg[m * 32 + tid]; mx = fmaxf(mx, v[m]); }
    float se = 0.f;
#pragma unroll
    for (int m = 0; m < 5; ++m) { v[m] = __expf(v[m] - mx); se += v[m]; }
    float inv = 1.f / se;
#pragma unroll
    for (int m = 0; m < 5; ++m) att[(long)lvl * 1280 + m * 256 + cb + tid] = v[m] * inv;
  }
}

// ---------------- weighted combine (merged levels) ----------------
__global__ __launch_bounds__(256) void k_combine(CmbP P) {
  constexpr int base[5] = {0, 2048, 2560, 2688, 2720};
  constexpr long ooff[4] = {0, 4194304, 5242880, 5505024};
  int bid = blockIdx.x + P.bid_base;
  int lvl = 0;
  while (bid >= base[lvl + 1]) ++lvl;
  int local = bid - base[lvl];
  const int HW = 16384 >> (2 * lvl);
  const int hw8s = 11 - 2 * lvl;
  int idx = local * 256 + threadIdx.x;
  int c = idx >> hw8s;
  int p = (idx & ((1 << hw8s) - 1)) << 3;
  const u16* feas = P.feas[lvl];
  const float* att = P.att + lvl * 1280;
  float* out = P.out + ooff[lvl];
  float a[5];
#pragma unroll
  for (int m = 0; m < 5; ++m) a[m] = att[m * 256 + c];
  float o[8] = {};
#pragma unroll
  for (int m = 0; m < 5; ++m) {
    u16x8 v = *(const u16x8*)(feas + (long)(m * 256 + c) * HW + p);
#pragma unroll
    for (int e = 0; e < 8; ++e) o[e] += a[m] * b2f(v[e]);
  }
  float* op = out + (long)c * HW + p;
  f32x4 v0 = {o[0], o[1], o[2], o[3]};
  f32x4 v1 = {o[4], o[5], o[6], o[7]};
  *(f32x4*)op = v0;
  *(f32x4*)(op + 4) = v1;
}

// ---------------- host ----------------
extern "C" void kernel_launch(void* const* d_in, const int* in_sizes, int n_in,
                              void* d_out, int out_size, void* d_ws, size_t ws_size,
                              hipStream_t stream) {
  (void)n_in; (void)out_size;
  static const int HWs[4] = {16384, 4096, 1024, 256};
  static const int Ws[4]  = {128, 64, 32, 16};
  static const int Cin[4] = {256, 512, 1024, 2048};
  static const long LToff[4] = {0, 4194304, 5242880, 5505024};
  static const long SBoff[4] = {0, 37748736, 47185920, 49545216};
  static const long Foff[4]  = {0, 20971520, 26214400, 27525120};
  static const long Loff[4]  = {0, 4194304, 6291456, 7340032};

  int xi[4], li[4];
  if (in_sizes[1] == 256 * 256) {
    for (int i = 0; i < 4; ++i) { xi[i] = 2 * i; li[i] = 2 * i + 1; }
  } else {
    for (int i = 0; i < 4; ++i) { xi[i] = i; li[i] = 4 + i; }
  }
  const float *x[4], *lw[4];
  for (int i = 0; i < 4; ++i) { x[i] = (const float*)d_in[xi[i]]; lw[i] = (const float*)d_in[li[i]]; }
  const float* lb    = (const float*)d_in[8];
  const float* aac_w = (const float*)d_in[9];
  const float* aac_b = (const float*)d_in[10];
  const float* bn_g  = (const float*)d_in[11];
  const float* bn_b  = (const float*)d_in[12];
  const float* bn_m  = (const float*)d_in[13];
  const float* bn_v  = (const float*)d_in[14];
  const float* fc_w  = (const float*)d_in[15];
  const float* fc_b  = (const float*)d_in[16];
  const float* fcs_w = (const float*)d_in[17];
  const float* fcs_b = (const float*)d_in[18];

  char* wp = (char*)d_ws;
  auto carve = [&](size_t bytes) { char* p = wp; wp += (bytes + 255) & ~(size_t)255; return p; };
  u16* xT[4];  for (int i = 0; i < 4; ++i) xT[i]  = (u16*)carve((size_t)HWs[i] * Cin[i] * 2);
  u16* lwb[4]; for (int i = 0; i < 4; ++i) lwb[i] = (u16*)carve((size_t)256 * Cin[i] * 2);
  u16* latT_all = (u16*)carve((size_t)5570560 * 2);
  u16* W9[4];  for (int i = 0; i < 4; ++i) W9[i]  = (u16*)carve((size_t)2304 * 256 * 2);
  float* fea_s = (float*)carve(4 * 256 * 4);
  float* att   = (float*)carve(4 * 5 * 256 * 4);
  size_t fixed = (size_t)(wp - (char*)d_ws);
  const size_t szSbAll   = (size_t)50135040 * 2;
  const size_t szFeasAll = (size_t)27852800 * 2;
  const size_t szSbSh    = (size_t)37748736 * 2;
  const size_t szFeasSh  = (size_t)20971520 * 2;
  bool tierA = fixed + szSbAll + szFeasAll + 1024 <= ws_size;

  u16* Sb;     // aliased as f32 split-K chunk buffers before Sb is written
  u16* feasB;
  if (tierA) { Sb = (u16*)carve(szSbAll); feasB = (u16*)carve(szFeasAll); }
  else       { Sb = (u16*)carve(szSbSh);  feasB = (u16*)carve(szFeasSh); }
  float* latF32 = (float*)Sb;

  hipMemsetAsync(fea_s, 0, 4 * 256 * 4, stream);

  // --- prep ---
  PrepP pp;
  for (int i = 0; i < 4; ++i) {
    pp.x[i] = x[i]; pp.xT[i] = xT[i]; pp.lw[i] = lw[i]; pp.lwb[i] = lwb[i]; pp.W9[i] = W9[i];
  }
  pp.aac_w = aac_w;
  k_prep<<<12544, 256, 0, stream>>>(pp);

  // --- lateral GEMM (split-K; L0 direct bf16) + finalize (L1-3) + top-down ---
  LatP lp;
  for (int i = 0; i < 4; ++i) { lp.A[i] = lwb[i]; lp.B[i] = xT[i]; lp.O[i] = latF32 + Loff[i]; }
  lp.bias0 = lb;
  lp.latT0 = latT_all;
  k_lat<<<480, 256, 0, stream>>>(lp);
  FinP fp;
  for (int i = 0; i < 4; ++i) fp.In[i] = latF32 + Loff[i];
  fp.bias = lb; fp.latT_all = latT_all;
  k_fin<<<672, 256, 0, stream>>>(fp);
  for (int i = 2; i >= 0; --i)
    k_ups_add<<<HWs[i] / 8, 256, 0, stream>>>(latT_all + LToff[i], latT_all + LToff[i + 1],
                                              Ws[i], HWs[i]);

  static const int cnt_s[4] = {2304, 576, 144, 36};
  static const int base_s[4] = {0, 2304, 2880, 3024};
  static const int cnt_g[4] = {2048, 512, 128, 32};
  static const int base_g[4] = {0, 2048, 2560, 2688};

  SgP sp;
  GatP gp;
  CmbP cp;
  for (int i = 0; i < 4; ++i) {
    sp.A[i] = W9[i];
    sp.B[i] = latT_all + LToff[i];
    sp.C[i] = tierA ? Sb + SBoff[i] : Sb;
    gp.S[i] = sp.C[i];
    gp.feas[i] = tierA ? feasB + Foff[i] : feasB;
    cp.feas[i] = gp.feas[i];
  }
  gp.fea_s = fea_s;
  gp.aac_b = aac_b; gp.bn_g = bn_g; gp.bn_b = bn_b; gp.bn_m = bn_m; gp.bn_v = bn_v;
  cp.att = att; cp.out = (float*)d_out;

  if (tierA) {
    sp.bid_base = 0; gp.bid_base = 0; cp.bid_base = 0;
    k_sgemm<<<3060, 256, 0, stream>>>(sp);
    k_gather<<<2720, 256, 0, stream>>>(gp);
    k_fc_att<<<32, 256, 0, stream>>>(0, fea_s, fc_w, fc_b, fcs_w, fcs_b, att);
    k_combine<<<2720, 256, 0, stream>>>(cp);
  } else {
    for (int i = 0; i < 4; ++i) {
      sp.bid_base = base_s[i];
      k_sgemm<<<cnt_s[i], 256, 0, stream>>>(sp);
      gp.bid_base = base_g[i];
      k_gather<<<cnt_g[i], 256, 0, stream>>>(gp);
      k_fc_att<<<8, 256, 0, stream>>>(i, fea_s, fc_w, fc_b, fcs_w, fcs_b, att);
      cp.bid_base = base_g[i];
      k_combine<<<cnt_g[i], 256, 0, stream>>>(cp);
    }
  }
}

// Round 7
// 275.284 us; speedup vs baseline: 1.1734x; 1.0449x over previous
//
#include <hip/hip_runtime.h>

// FPN_AAR: FPN lateral/top-down + AdaptiveAngleConv (5 rotated 3x3) + SK fusion.
// Rotations are permutations of one kernel -> compute 9 tap planes
// S[s] = W[:,:,s] @ lat (one GEMM), then each rotation is a 9-term shifted
// gather of the planes (5x FLOP reduction vs direct conv).
// R7: gather issues all 23 plane-row loads upfront (latency overlap; S stored
//     [c][9][HW] for locality); top-down pathway folded into one k_fin2 kernel
//     (up2 composes: final_i = sum_j up_{2^(j-i)}(l_j)).

typedef unsigned short u16;
typedef unsigned int   u32;
typedef __bf16 bf16x8 __attribute__((ext_vector_type(8)));
typedef float  f32x4  __attribute__((ext_vector_type(4)));
typedef u16    u16x8  __attribute__((ext_vector_type(8)));
typedef u16    u16x4  __attribute__((ext_vector_type(4)));

__device__ __forceinline__ u16 f2b(float f) {  // f32 -> bf16 RNE
  u32 u = __builtin_bit_cast(u32, f);
  return (u16)((u + 0x7fffu + ((u >> 16) & 1u)) >> 16);
}
__device__ __forceinline__ float b2f(u16 h) {
  u32 u = ((u32)h) << 16;
  return __builtin_bit_cast(float, u);
}

constexpr int ROT[5][9] = {
  {0,1,2,3,4,5,6,7,8},
  {3,0,1,6,4,2,7,8,5},
  {6,3,0,7,4,1,8,5,2},
  {7,6,3,8,4,0,5,2,1},
  {8,7,6,5,4,3,2,1,0}};

// raw[] register index for used (plane s, dy) pairs; -1 = unused by any rotation
constexpr int IDX[9][3] = {
  {0, 1, 2}, {3, 4, 5}, {6, 7, 8}, {9, 10, -1}, {-1, 11, -1},
  {-1, 12, 13}, {14, 15, 16}, {17, 18, 19}, {20, 21, 22}};

__device__ __forceinline__ void glds16(const u16* g, u16* l) {
  __builtin_amdgcn_global_load_lds((const __attribute__((address_space(1))) void*)g,
                                   (__attribute__((address_space(3))) void*)l, 16, 0, 0);
}

// ---------------- param structs ----------------
struct PrepP {
  const float* x[4]; u16* xT[4];
  const float* lw[4]; u16* lwb[4];
  const float* aac_w; u16* W9[4];
};
struct LatP { const u16* A[4]; const u16* B[4]; float* O[4];
              const float* bias0; u16* latT0; };
struct FinP { const float* In[4]; const float* bias; u16* latT_all; };
struct SgP  { const u16* A[4]; const u16* B[4]; u16* C[4]; int bid_base; };
struct GatP { const u16* S[4]; u16* feas[4]; float* fea_s;
              const float* aac_b; const float* bn_g; const float* bn_b;
              const float* bn_m; const float* bn_v; int bid_base; };
struct CmbP { const u16* feas[4]; const float* att; float* out; int bid_base; };

// ---------------- merged prep: transpose + lw cvt + W9 permute ----------------
__global__ __launch_bounds__(256) void k_prep(PrepP P) {
  const int bid = blockIdx.x;
  const int tid = threadIdx.x;
  if (bid < 7680) {              // transpose f32 [C][P] -> bf16 [P][C]
    __shared__ u16 t[32][33];
    int lvl, local;
    if (bid < 4096)      { lvl = 0; local = bid; }
    else if (bid < 6144) { lvl = 1; local = bid - 4096; }
    else if (bid < 7168) { lvl = 2; local = bid - 6144; }
    else                 { lvl = 3; local = bid - 7168; }
    const float* src = P.x[lvl];
    u16* dst = P.xT[lvl];
    const int Pp = 16384 >> (2 * lvl);
    const int C = 256 << lvl;
    const int pbs = 9 - 2 * lvl;          // log2(P/32)
    int bx = local & ((1 << pbs) - 1), by = local >> pbs;
    int p0 = bx * 32, c0 = by * 32;
    int tx = tid & 31, ty = tid >> 5;
#pragma unroll
    for (int j = 0; j < 4; ++j)
      t[ty + 8 * j][tx] = f2b(src[(long)(c0 + ty + 8 * j) * Pp + p0 + tx]);
    __syncthreads();
#pragma unroll
    for (int j = 0; j < 4; ++j)
      dst[(long)(p0 + ty + 8 * j) * C + c0 + tx] = t[tx][ty + 8 * j];
  } else if (bid < 11520) {      // lw f32 -> bf16
    int i = (bid - 7680) * 256 + tid;
    const float* src; u16* dst; int off;
    if (i < 65536)       { src = P.lw[0]; dst = P.lwb[0]; off = i; }
    else if (i < 196608) { src = P.lw[1]; dst = P.lwb[1]; off = i - 65536; }
    else if (i < 458752) { src = P.lw[2]; dst = P.lwb[2]; off = i - 196608; }
    else                 { src = P.lw[3]; dst = P.lwb[3]; off = i - 458752; }
    dst[off] = f2b(src[off]);
  } else {                       // aac_w [4][256][256][9] -> W9 [(s*256+oc)][ic]
    int gid = (bid - 11520) * 256 + tid;
    int lvl = gid >> 16, idx = gid & 65535;
    u16* out = P.W9[lvl];
    const float* src = P.aac_w + (long)lvl * 589824 + (long)idx * 9;
    int oc = idx >> 8, ic = idx & 255;
    float v[9];
#pragma unroll
    for (int s = 0; s < 9; ++s) v[s] = src[s];
#pragma unroll
    for (int s = 0; s < 9; ++s) out[(long)((s << 8) + oc) * 256 + ic] = f2b(v[s]);
  }
}

// ---------------- lateral GEMM, split-K (chunk = 256) -------------------------
// lvl 0 has a single K-chunk: write bf16 transposed + bias directly.
__global__ __launch_bounds__(256) void k_lat(LatP P) {
  constexpr int base[5] = {0, 256, 384, 448, 480};
  constexpr int NTS[4] = {7, 5, 3, 1};   // log2(N/128)
  int bid = blockIdx.x;
  int lvl = 0;
  while (bid >= base[lvl + 1]) ++lvl;
  int local = bid - base[lvl];
  const int nts = NTS[lvl];
  const int kc = local >> (nts + 1);
  const int r = local & ((2 << nts) - 1);
  const int by = r >> nts, bx = r & ((1 << nts) - 1);
  const int N = 16384 >> (2 * lvl);
  const long KF = 256 << lvl;
  const long kq = (long)kc * 256;
  const u16* A = P.A[lvl];
  const u16* B = P.B[lvl];
  float* O = P.O[lvl] + (long)kc * N * 256;

  __shared__ alignas(16) u16 As[128 * 32];
  __shared__ alignas(16) u16 Bs[128 * 32];
  const int tid = threadIdx.x;
  const int wid = tid >> 6, lane = tid & 63;
  const int wr = wid >> 1, wc = wid & 1;
  const int m0 = by * 128, n0 = bx * 128;
  const int lr = lane & 15, lk = lane >> 4;
  f32x4 acc[4][4] = {};
  const int t0 = wid * 2;
  const int srow = lane >> 2, scol = (lane & 3) * 8;
  const u16* gA0 = A + (long)(m0 + t0 * 16 + srow) * KF + kq + scol;
  const u16* gA1 = A + (long)(m0 + t0 * 16 + 16 + srow) * KF + kq + scol;
  const u16* gB0 = B + (long)(n0 + t0 * 16 + srow) * KF + kq + scol;
  const u16* gB1 = B + (long)(n0 + t0 * 16 + 16 + srow) * KF + kq + scol;
  u16* lA0 = As + t0 * 512;
  u16* lA1 = As + t0 * 512 + 512;
  u16* lB0 = Bs + t0 * 512;
  u16* lB1 = Bs + t0 * 512 + 512;
  for (int kt = 0; kt < 256; kt += 32) {
    glds16(gA0 + kt, lA0);
    glds16(gA1 + kt, lA1);
    glds16(gB0 + kt, lB0);
    glds16(gB1 + kt, lB1);
    __syncthreads();
    bf16x8 af[4], bfr[4];
#pragma unroll
    for (int m = 0; m < 4; ++m)
      af[m] = *(const bf16x8*)(As + (wr * 64 + m * 16 + lr) * 32 + lk * 8);
#pragma unroll
    for (int n = 0; n < 4; ++n)
      bfr[n] = *(const bf16x8*)(Bs + (wc * 64 + n * 16 + lr) * 32 + lk * 8);
#pragma unroll
    for (int m = 0; m < 4; ++m)
#pragma unroll
      for (int n = 0; n < 4; ++n)
        acc[m][n] = __builtin_amdgcn_mfma_f32_16x16x32_bf16(af[m], bfr[n], acc[m][n], 0, 0, 0);
    __syncthreads();
  }
  if (lvl == 0) {                        // single chunk: direct bf16 + bias
#pragma unroll
    for (int m = 0; m < 4; ++m) {
      int row = m0 + wr * 64 + m * 16 + lk * 4;
      f32x4 bv = *(const f32x4*)(P.bias0 + row);
#pragma unroll
      for (int n = 0; n < 4; ++n) {
        int col = n0 + wc * 64 + n * 16 + lr;
        u16x4 o;
#pragma unroll
        for (int i = 0; i < 4; ++i) o[i] = f2b(acc[m][n][i] + bv[i]);
        *(u16x4*)(P.latT0 + (long)col * 256 + row) = o;
      }
    }
  } else {
#pragma unroll
    for (int m = 0; m < 4; ++m) {
      int row = m0 + wr * 64 + m * 16 + lk * 4;   // oc
#pragma unroll
      for (int n = 0; n < 4; ++n) {
        int col = n0 + wc * 64 + n * 16 + lr;     // pixel
        *(f32x4*)(O + (long)col * 256 + row) = acc[m][n];
      }
    }
  }
}

// ---------------- fused top-down finalize: final_i = sum_j up_{2^(j-i)}(l_j) --
// l_0 comes bias-applied bf16 from k_lat (in latT_all); l_1..3 are split-K f32
// chunk sums + bias. One launch computes every level's final lateral.
__global__ __launch_bounds__(256) void k_fin2(FinP P) {
  constexpr long eb[5] = {0, 4194304, 5242880, 5505024, 5570560};
  long idx = ((long)blockIdx.x * 256 + threadIdx.x) * 8;
  int lvl = 0;
  while (idx >= eb[lvl + 1]) ++lvl;
  long local = idx - eb[lvl];
  const int p = (int)(local >> 8);
  const int oc = (int)(local & 255);
  const int lw = 7 - lvl;                 // log2 W_i
  const int y = p >> lw, x = p & ((1 << lw) - 1);
  f32x4 a0 = {0.f, 0.f, 0.f, 0.f}, a1 = {0.f, 0.f, 0.f, 0.f};
  if (lvl == 0) {
    u16x8 v = *(const u16x8*)(P.latT_all + idx);
#pragma unroll
    for (int e = 0; e < 4; ++e) { a0[e] = b2f(v[e]); a1[e] = b2f(v[4 + e]); }
  }
  for (int j = (lvl == 0 ? 1 : lvl); j <= 3; ++j) {
    int sh = j - lvl;
    int ys = y >> sh, xs = x >> sh;
    int wj = 7 - j;
    long lj = ((long)((ys << wj) + xs) << 8) + oc;
    const float* in = P.In[j] + lj;
    const long cstride = (long)(16384 >> (2 * j)) * 256;
    const int chunks = 1 << j;
    for (int k = 0; k < chunks; ++k) {
      a0 += *(const f32x4*)(in + k * cstride);
      a1 += *(const f32x4*)(in + k * cstride + 4);
    }
    a0 += *(const f32x4*)(P.bias + j * 256 + oc);
    a1 += *(const f32x4*)(P.bias + j * 256 + oc + 4);
  }
  u16x8 o;
#pragma unroll
  for (int e = 0; e < 4; ++e) { o[e] = f2b(a0[e]); o[4 + e] = f2b(a1[e]); }
  *(u16x8*)(P.latT_all + idx) = o;
}

// ---------------- S-GEMM, XCD-swizzled; C stored [c][9][HW] for gather -------
__global__ __launch_bounds__(256) void k_sgemm(SgP P) {
  constexpr int base[5] = {0, 2304, 2880, 3024, 3060};
  constexpr int cntv[4] = {2304, 576, 144, 36};
  int bid = blockIdx.x + P.bid_base;
  int lvl = 0;
  while (bid >= base[lvl + 1]) ++lvl;
  int local = bid - base[lvl];
  if (lvl < 3) {                      // bijective XCD chunking (cnt % 8 == 0)
    int q = cntv[lvl] >> 3;
    local = (local & 7) * q + (local >> 3);
  }
  const int bx = local / 18, by = local - bx * 18;   // by fastest: B-panel reuse
  const int N = 16384 >> (2 * lvl);
  const u16* A = P.A[lvl];
  const u16* B = P.B[lvl];
  u16* C = P.C[lvl];

  __shared__ alignas(16) u16 As[128 * 32];
  __shared__ alignas(16) u16 Bs[128 * 32];
  const int tid = threadIdx.x;
  const int wid = tid >> 6, lane = tid & 63;
  const int wr = wid >> 1, wc = wid & 1;
  const int m0 = by * 128, n0 = bx * 128;
  const int lr = lane & 15, lk = lane >> 4;
  f32x4 acc[4][4] = {};
  const int t0 = wid * 2;
  const int srow = lane >> 2, scol = (lane & 3) * 8;
  const u16* gA0 = A + (long)(m0 + t0 * 16 + srow) * 256 + scol;
  const u16* gA1 = A + (long)(m0 + t0 * 16 + 16 + srow) * 256 + scol;
  const u16* gB0 = B + (long)(n0 + t0 * 16 + srow) * 256 + scol;
  const u16* gB1 = B + (long)(n0 + t0 * 16 + 16 + srow) * 256 + scol;
  u16* lA0 = As + t0 * 512;
  u16* lA1 = As + t0 * 512 + 512;
  u16* lB0 = Bs + t0 * 512;
  u16* lB1 = Bs + t0 * 512 + 512;
  for (int kt = 0; kt < 256; kt += 32) {
    glds16(gA0 + kt, lA0);
    glds16(gA1 + kt, lA1);
    glds16(gB0 + kt, lB0);
    glds16(gB1 + kt, lB1);
    __syncthreads();
    bf16x8 af[4], bfr[4];
#pragma unroll
    for (int m = 0; m < 4; ++m)
      af[m] = *(const bf16x8*)(As + (wr * 64 + m * 16 + lr) * 32 + lk * 8);
#pragma unroll
    for (int n = 0; n < 4; ++n)
      bfr[n] = *(const bf16x8*)(Bs + (wc * 64 + n * 16 + lr) * 32 + lk * 8);
#pragma unroll
    for (int m = 0; m < 4; ++m)
#pragma unroll
      for (int n = 0; n < 4; ++n)
        acc[m][n] = __builtin_amdgcn_mfma_f32_16x16x32_bf16(af[m], bfr[n], acc[m][n], 0, 0, 0);
    __syncthreads();
  }
#pragma unroll
  for (int m = 0; m < 4; ++m) {
    int row = m0 + wr * 64 + m * 16 + lk * 4;
#pragma unroll
    for (int n = 0; n < 4; ++n) {
      int col = n0 + wc * 64 + n * 16 + lr;
#pragma unroll
      for (int i = 0; i < 4; ++i) {
        int rr = row + i;                 // = s*256 + oc
        C[((long)((rr & 255) * 9 + (rr >> 8))) * N + col] = f2b(acc[m][n][i]);
      }
    }
  }
}

// ---------------- streaming gather, all loads upfront -------------------------
// Block = (channel(s), y-band); thread owns 8 consecutive px of one row. All 23
// used (plane,dy) row-loads issue before any use (one latency wait, ~35KB/CU in
// flight). S is [c][9][HW]: a block's streams sit in one contiguous region.
// x-halo via shfl within row-groups (group boundary == image border).
template <int LVL>
__device__ __forceinline__ void gather_stream(int local_bid, const GatP& P) {
  constexpr int W = 128 >> LVL, H = W, HW = W * W;
  constexpr int XL = 16 >> LVL;                    // lanes per row (8 px each)
  constexpr int LX = 4 - LVL;                      // log2 XL
  constexpr int YB = (LVL == 0 || LVL == 3) ? 16 : 32;
  constexpr int LY = (LVL == 0 || LVL == 3) ? 4 : 5;
  constexpr int NB = H / YB;                       // y-bands (8,2,1,1)
  constexpr int CPB = 256 / (XL * YB);             // channels/block (1,1,2,8)
  const int tid = threadIdx.x;
  const int xc = tid & (XL - 1);
  const int yloc = (tid >> LX) & (YB - 1);
  const int csub = tid >> (LX + LY);
  const int band = local_bid & (NB - 1);
  const int c = (local_bid / NB) * CPB + csub;
  const int y = band * YB + yloc;
  const u16* Sb = P.S[LVL] + (long)c * 9 * HW + (long)y * W + xc * 8;
  const bool hasm = (y > 0), hasp = (y < H - 1);

  // ---- issue all 23 loads ----
  u16x8 raw[23];
  constexpr u16x8 Z = {0, 0, 0, 0, 0, 0, 0, 0};
#pragma unroll
  for (int s = 0; s < 9; ++s) {
    const u16* bp = Sb + (long)s * HW;
#pragma unroll
    for (int dy = 0; dy < 3; ++dy) {
      if (IDX[s][dy] < 0) continue;                // compile-time folded
      u16x8 v = Z;
      if (dy == 0)      { if (hasm) v = *(const u16x8*)(bp - W); }
      else if (dy == 1) { v = *(const u16x8*)bp; }
      else              { if (hasp) v = *(const u16x8*)(bp + W); }
      raw[IDX[s][dy]] = v;
    }
  }

  float sc[5], sh[5];
#pragma unroll
  for (int m = 0; m < 5; ++m) {
    float g = P.bn_g[LVL * 1280 + m * 256 + c], bb = P.bn_b[LVL * 1280 + m * 256 + c];
    float mu = P.bn_m[LVL * 1280 + m * 256 + c], vv = P.bn_v[LVL * 1280 + m * 256 + c];
    float s = g * rsqrtf(vv + 1e-5f);
    sc[m] = s; sh[m] = bb - mu * s;
  }
  const float ab = P.aac_b[LVL * 256 + c];
  float val[5][8];
#pragma unroll
  for (int m = 0; m < 5; ++m)
#pragma unroll
    for (int e = 0; e < 8; ++e) val[m][e] = ab;

  // ---- process (same order as issue: fine-grained vmcnt waits) ----
#pragma unroll
  for (int s = 0; s < 9; ++s) {
#pragma unroll
    for (int dy = 0; dy < 3; ++dy) {
      if (IDX[s][dy] < 0) continue;
      u16x8 v = raw[IDX[s][dy]];
      float f[8];
#pragma unroll
      for (int j = 0; j < 8; ++j) f[j] = b2f(v[j]);
      float left = __shfl_up(f[7], 1);
      float right = __shfl_down(f[0], 1);
      if (xc == 0) left = 0.f;
      if (xc == XL - 1) right = 0.f;
      float wv[10];
      wv[0] = left;
#pragma unroll
      for (int j = 0; j < 8; ++j) wv[j + 1] = f[j];
      wv[9] = right;
#pragma unroll
      for (int m = 0; m < 5; ++m)
#pragma unroll
        for (int dx = 0; dx < 3; ++dx)
          if (ROT[m][dy * 3 + dx] == s) {
#pragma unroll
            for (int e = 0; e < 8; ++e) val[m][e] += wv[e + dx];
          }
    }
  }

  float lsum = 0.f;
  u16* F = P.feas[LVL];
#pragma unroll
  for (int m = 0; m < 5; ++m) {
    u16x8 o;
#pragma unroll
    for (int e = 0; e < 8; ++e) {
      float r = fmaxf(val[m][e] * sc[m] + sh[m], 0.f);
      o[e] = f2b(r);
      lsum += r;
    }
    *(u16x8*)(F + (long)(m * 256 + c) * HW + (long)y * W + xc * 8) = o;
  }
  constexpr int RG = (LVL == 3) ? 32 : 64;         // lanes sharing one channel
#pragma unroll
  for (int off = RG >> 1; off > 0; off >>= 1) lsum += __shfl_xor(lsum, off);
  if ((tid & (RG - 1)) == 0) atomicAdd(P.fea_s + LVL * 256 + c, lsum);
}

__global__ __launch_bounds__(256) void k_gather(GatP P) {
  int bid = blockIdx.x + P.bid_base;
  if (bid < 2048) gather_stream<0>(bid, P);
  else if (bid < 2560) gather_stream<1>(bid - 2048, P);
  else if (bid < 2688) gather_stream<2>(bid - 2560, P);
  else gather_stream<3>(bid - 2688, P);
}

// ---------------- FC + softmax attention (c-split: 8 blocks / level) ----------
__global__ __launch_bounds__(256) void k_fc_att(int lvl0, const float* __restrict__ fea_s,
                                                const float* __restrict__ fc_w,
                                                const float* __restrict__ fc_b,
                                                const float* __restrict__ fcs_w,
                                                const float* __restrict__ fcs_b,
                                                float* __restrict__ att) {
  const int lvl = lvl0 + (blockIdx.x >> 3);
  const int cb = (blockIdx.x & 7) * 32;
  const float inv_hw = 1.f / (float)(16384 >> (2 * lvl));
  __shared__ float ss[256], zs[128], lg[160];
  const int tid = threadIdx.x;
  ss[tid] = fea_s[lvl * 256 + tid] * inv_hw;
  __syncthreads();
  if (tid < 128) {                     // z = fc_b + fc_w @ ss (redundant per block)
    const f32x4* w4 = (const f32x4*)(fc_w + (long)lvl * 32768 + (long)tid * 256);
    float z = fc_b[lvl * 128 + tid];
#pragma unroll 8
    for (int j = 0; j < 64; ++j) {
      f32x4 w = w4[j];
      z += ss[4 * j] * w[0] + ss[4 * j + 1] * w[1] + ss[4 * j + 2] * w[2] + ss[4 * j + 3] * w[3];
    }
    zs[tid] = z;
  }
  __syncthreads();
  if (tid < 160) {                     // logits for this block's 32 channels
    int m = tid >> 5, ci = tid & 31;
    long row = (long)lvl * 1280 + m * 256 + cb + ci;
    const f32x4* w4 = (const f32x4*)(fcs_w + row * 128);
    float l = fcs_b[row];
#pragma unroll 8
    for (int d4 = 0; d4 < 32; ++d4) {
      f32x4 w = w4[d4];
      l += zs[4 * d4] * w[0] + zs[4 * d4 + 1] * w[1] + zs[4 * d4 + 2] * w[2] + zs[4 * d4 + 3] * w[3];
    }
    lg[tid] = l;
  }
  __syncthreads();
  if (tid < 32) {
    float v[5], mx = -1e30f;
#pragma unroll
    for (int m = 0; m < 5; ++m) { v[m] = lg[m * 32 + tid]; mx = fmaxf(mx, v[m]); }
    float se = 0.f;
#pragma unroll
    for (int m = 0; m < 5; ++m) { v[m] = __expf(v[m] - mx); se += v[m]; }
    float inv = 1.f / se;
#pragma unroll
    for (int m = 0; m < 5; ++m) att[(long)lvl * 1280 + m * 256 + cb + tid] = v[m] * inv;
  }
}

// ---------------- weighted combine (merged levels) ----------------
__global__ __launch_bounds__(256) void k_combine(CmbP P) {
  constexpr int base[5] = {0, 2048, 2560, 2688, 2720};
  constexpr long ooff[4] = {0, 4194304, 5242880, 5505024};
  int bid = blockIdx.x + P.bid_base;
  int lvl = 0;
  while (bid >= base[lvl + 1]) ++lvl;
  int local = bid - base[lvl];
  const int HW = 16384 >> (2 * lvl);
  const int hw8s = 11 - 2 * lvl;
  int idx = local * 256 + threadIdx.x;
  int c = idx >> hw8s;
  int p = (idx & ((1 << hw8s) - 1)) << 3;
  const u16* feas = P.feas[lvl];
  const float* att = P.att + lvl * 1280;
  float* out = P.out + ooff[lvl];
  float a[5];
#pragma unroll
  for (int m = 0; m < 5; ++m) a[m] = att[m * 256 + c];
  float o[8] = {};
#pragma unroll
  for (int m = 0; m < 5; ++m) {
    u16x8 v = *(const u16x8*)(feas + (long)(m * 256 + c) * HW + p);
#pragma unroll
    for (int e = 0; e < 8; ++e) o[e] += a[m] * b2f(v[e]);
  }
  float* op = out + (long)c * HW + p;
  f32x4 v0 = {o[0], o[1], o[2], o[3]};
  f32x4 v1 = {o[4], o[5], o[6], o[7]};
  *(f32x4*)op = v0;
  *(f32x4*)(op + 4) = v1;
}

// ---------------- host ----------------
extern "C" void kernel_launch(void* const* d_in, const int* in_sizes, int n_in,
                              void* d_out, int out_size, void* d_ws, size_t ws_size,
                              hipStream_t stream) {
  (void)n_in; (void)out_size;
  static const int HWs[4] = {16384, 4096, 1024, 256};
  static const int Cin[4] = {256, 512, 1024, 2048};
  static const long LToff[4] = {0, 4194304, 5242880, 5505024};
  static const long SBoff[4] = {0, 37748736, 47185920, 49545216};
  static const long Foff[4]  = {0, 20971520, 26214400, 27525120};
  static const long Loff[4]  = {0, 4194304, 6291456, 7340032};

  int xi[4], li[4];
  if (in_sizes[1] == 256 * 256) {
    for (int i = 0; i < 4; ++i) { xi[i] = 2 * i; li[i] = 2 * i + 1; }
  } else {
    for (int i = 0; i < 4; ++i) { xi[i] = i; li[i] = 4 + i; }
  }
  const float *x[4], *lw[4];
  for (int i = 0; i < 4; ++i) { x[i] = (const float*)d_in[xi[i]]; lw[i] = (const float*)d_in[li[i]]; }
  const float* lb    = (const float*)d_in[8];
  const float* aac_w = (const float*)d_in[9];
  const float* aac_b = (const float*)d_in[10];
  const float* bn_g  = (const float*)d_in[11];
  const float* bn_b  = (const float*)d_in[12];
  const float* bn_m  = (const float*)d_in[13];
  const float* bn_v  = (const float*)d_in[14];
  const float* fc_w  = (const float*)d_in[15];
  const float* fc_b  = (const float*)d_in[16];
  const float* fcs_w = (const float*)d_in[17];
  const float* fcs_b = (const float*)d_in[18];

  char* wp = (char*)d_ws;
  auto carve = [&](size_t bytes) { char* p = wp; wp += (bytes + 255) & ~(size_t)255; return p; };
  u16* xT[4];  for (int i = 0; i < 4; ++i) xT[i]  = (u16*)carve((size_t)HWs[i] * Cin[i] * 2);
  u16* lwb[4]; for (int i = 0; i < 4; ++i) lwb[i] = (u16*)carve((size_t)256 * Cin[i] * 2);
  u16* latT_all = (u16*)carve((size_t)5570560 * 2);
  u16* W9[4];  for (int i = 0; i < 4; ++i) W9[i]  = (u16*)carve((size_t)2304 * 256 * 2);
  float* fea_s = (float*)carve(4 * 256 * 4);
  float* att   = (float*)carve(4 * 5 * 256 * 4);
  size_t fixed = (size_t)(wp - (char*)d_ws);
  const size_t szSbAll   = (size_t)50135040 * 2;
  const size_t szFeasAll = (size_t)27852800 * 2;
  const size_t szSbSh    = (size_t)37748736 * 2;
  const size_t szFeasSh  = (size_t)20971520 * 2;
  bool tierA = fixed + szSbAll + szFeasAll + 1024 <= ws_size;

  u16* Sb;     // aliased as f32 split-K chunk buffers before Sb is written
  u16* feasB;
  if (tierA) { Sb = (u16*)carve(szSbAll); feasB = (u16*)carve(szFeasAll); }
  else       { Sb = (u16*)carve(szSbSh);  feasB = (u16*)carve(szFeasSh); }
  float* latF32 = (float*)Sb;

  hipMemsetAsync(fea_s, 0, 4 * 256 * 4, stream);

  // --- prep ---
  PrepP pp;
  for (int i = 0; i < 4; ++i) {
    pp.x[i] = x[i]; pp.xT[i] = xT[i]; pp.lw[i] = lw[i]; pp.lwb[i] = lwb[i]; pp.W9[i] = W9[i];
  }
  pp.aac_w = aac_w;
  k_prep<<<12544, 256, 0, stream>>>(pp);

  // --- lateral GEMM (split-K; L0 direct bf16) + fused top-down finalize ---
  LatP lp;
  for (int i = 0; i < 4; ++i) { lp.A[i] = lwb[i]; lp.B[i] = xT[i]; lp.O[i] = latF32 + Loff[i]; }
  lp.bias0 = lb;
  lp.latT0 = latT_all;
  k_lat<<<480, 256, 0, stream>>>(lp);
  FinP fp;
  for (int i = 0; i < 4; ++i) fp.In[i] = latF32 + Loff[i];
  fp.bias = lb; fp.latT_all = latT_all;
  k_fin2<<<2720, 256, 0, stream>>>(fp);

  static const int cnt_s[4] = {2304, 576, 144, 36};
  static const int base_s[4] = {0, 2304, 2880, 3024};
  static const int cnt_g[4] = {2048, 512, 128, 32};
  static const int base_g[4] = {0, 2048, 2560, 2688};

  SgP sp;
  GatP gp;
  CmbP cp;
  for (int i = 0; i < 4; ++i) {
    sp.A[i] = W9[i];
    sp.B[i] = latT_all + LToff[i];
    sp.C[i] = tierA ? Sb + SBoff[i] : Sb;
    gp.S[i] = sp.C[i];
    gp.feas[i] = tierA ? feasB + Foff[i] : feasB;
    cp.feas[i] = gp.feas[i];
  }
  gp.fea_s = fea_s;
  gp.aac_b = aac_b; gp.bn_g = bn_g; gp.bn_b = bn_b; gp.bn_m = bn_m; gp.bn_v = bn_v;
  cp.att = att; cp.out = (float*)d_out;

  if (tierA) {
    sp.bid_base = 0; gp.bid_base = 0; cp.bid_base = 0;
    k_sgemm<<<3060, 256, 0, stream>>>(sp);
    k_gather<<<2720, 256, 0, stream>>>(gp);
    k_fc_att<<<32, 256, 0, stream>>>(0, fea_s, fc_w, fc_b, fcs_w, fcs_b, att);
    k_combine<<<2720, 256, 0, stream>>>(cp);
  } else {
    for (int i = 0; i < 4; ++i) {
      sp.bid_base = base_s[i];
      k_sgemm<<<cnt_s[i], 256, 0, stream>>>(sp);
      gp.bid_base = base_g[i];
      k_gather<<<cnt_g[i], 256, 0, stream>>>(gp);
      k_fc_att<<<8, 256, 0, stream>>>(i, fea_s, fc_w, fc_b, fcs_w, fcs_b, att);
      cp.bid_base = base_g[i];
      k_combine<<<cnt_g[i], 256, 0, stream>>>(cp);
    }
  }
}